// Round 5
// baseline (149.852 us; speedup 1.0000x reference)
//
#include <hip/hip_runtime.h>

// Problem constants (fixed by reference: B=32,D=64,H=32,W=32,K=2048)
#define N_PIX 32768   // B*H*W
#define DIM   64
#define KCODE 2048

typedef __attribute__((ext_vector_type(8))) short bf16x8;   // 8 bf16 = 4 VGPR
typedef __attribute__((ext_vector_type(4))) float f32x4;    // MFMA C/D

// bf16 round-to-nearest-even (manual, deterministic)
__device__ inline unsigned short f2bf(float v) {
    unsigned int u = __float_as_uint(v);
    return (unsigned short)((u + 0x7FFFu + ((u >> 16) & 1u)) >> 16);
}
__device__ inline float bf2f(unsigned short b) {
    return __uint_as_float(((unsigned int)b) << 16);
}

// ---------------------------------------------------------------------------
// Fused convert: blocks 0..127 split laten into 3 bf16 planes (fragment-major
// 256B units: [m 0..15][j 0..7]); blocks 128..135 split codebook + e_sq.
// x = h+m+l, representation error ~2^-27|x|.
// ---------------------------------------------------------------------------
__global__ __launch_bounds__(256)
void convert_kernel(const float* __restrict__ laten, const float* __restrict__ cb,
                    unsigned short* __restrict__ Ag, unsigned short* __restrict__ Bg,
                    float* __restrict__ esq) {
    const int tid = threadIdx.x;
    if (blockIdx.x < 128) {
        const int p  = blockIdx.x * 256 + tid;          // pixel id
        const int b  = p >> 10, hw = p & 1023;
        const float* src = laten + (((size_t)b << 6) << 10) + hw;
        const int mtile = p >> 4, mi = p & 15;
        char* outb = (char*)Ag;
#pragma unroll
        for (int kb = 0; kb < 8; ++kb) {
            alignas(16) unsigned short hv[8], mv[8], lv[8];
#pragma unroll
            for (int j = 0; j < 8; ++j) {
                float v = src[(size_t)(kb * 8 + j) << 10];   // coalesced
                unsigned short h = f2bf(v);
                float r1 = v - bf2f(h);
                unsigned short m = f2bf(r1);
                unsigned short l = f2bf(r1 - bf2f(m));
                hv[j] = h; mv[j] = m; lv[j] = l;
            }
            size_t u = ((((size_t)mtile) * 8 + kb) << 8) + mi * 16;
            *(uint4*)(outb + u)           = *(uint4*)hv;     // plane h
            *(uint4*)(outb + 4194304 + u) = *(uint4*)mv;     // plane m
            *(uint4*)(outb + 8388608 + u) = *(uint4*)lv;     // plane l
        }
    } else {
        const int n = (blockIdx.x - 128) * 256 + tid;   // code id
        const float* src = cb + (size_t)n * DIM;
        const int ntile = n >> 4, ni = n & 15;
        char* outb = (char*)Bg;
        float s = 0.f;
#pragma unroll
        for (int kb = 0; kb < 8; ++kb) {
            alignas(16) unsigned short hv[8], mv[8], lv[8];
#pragma unroll
            for (int j = 0; j < 8; ++j) {
                float v = src[kb * 8 + j];
                s = fmaf(v, v, s);
                unsigned short h = f2bf(v);
                float r1 = v - bf2f(h);
                unsigned short m = f2bf(r1);
                unsigned short l = f2bf(r1 - bf2f(m));
                hv[j] = h; mv[j] = m; lv[j] = l;
            }
            size_t u = ((((size_t)ntile) * 8 + kb) << 8) + ni * 16;
            *(uint4*)(outb + u)          = *(uint4*)hv;      // plane stride 256 KB
            *(uint4*)(outb + 262144 + u) = *(uint4*)mv;
            *(uint4*)(outb + 524288 + u) = *(uint4*)lv;
        }
        esq[n] = s;
    }
}

// ---------------------------------------------------------------------------
// Fused dist+argmin+gather. Grid 256 blocks (1/CU), block 512 = 8 waves
// (wm 2 x wn 4). Block owns 128 pixels x ALL 2048 codes.
//   - A frags (3 planes x 4 mt x 2 ks) live in 96 VGPRs for the whole kernel.
//   - 16 iters of 128 codes: B tile (48 KB, 3 planes) streamed through LDS,
//     next tile register-prefetched during MFMAs (loads in flight across
//     the compute; vmcnt waited only at the next ds_write).
//   - 6 bf16 MFMA passes (hl,lh,mm,hm,mh,hh small->large), exact to ~2^-35.
//   - Per-lane running argmin (n ascending -> strict <), shfl col-reduce,
//     LDS wn-reduce with index tie-break == numpy first-min semantics.
//   - Epilogue writes idx + gathers fp32 codebook rows directly to out.
// ---------------------------------------------------------------------------
__global__ __launch_bounds__(512, 2)
void dist_fused_kernel(const unsigned short* __restrict__ Ag,
                       const unsigned short* __restrict__ Bg,
                       const float* __restrict__ esq,
                       const float* __restrict__ cb,
                       float* __restrict__ out0, float* __restrict__ out1) {
    __shared__ char  Bs[49152];     // 48 KB B tile; aliased as scratch after loop
    __shared__ float esqS[2048];    // 8 KB

    const int tid  = threadIdx.x;
    const int lane = tid & 63, wave = tid >> 6;
    const int wm = wave & 1, wn = wave >> 1;         // 2 x 4 wave grid
    const int quad = lane >> 4, col = lane & 15;
    const int bx = blockIdx.x;
    const int mtile0 = bx * 8;

    // stage e_sq to LDS (read 2/lane/iter later)
    for (int i = tid; i < 2048; i += 512) esqS[i] = esq[i];

    // ---- A fragments: 3 planes x 4 mt x 2 ks, resident in VGPRs ----
    const char* AgB = (const char*)Ag;
    bf16x8 af[3][4][2];
#pragma unroll
    for (int pl = 0; pl < 3; ++pl)
#pragma unroll
        for (int mt = 0; mt < 4; ++mt)
#pragma unroll
            for (int ks = 0; ks < 2; ++ks)
                af[pl][mt][ks] = *(const bf16x8*)(AgB + (size_t)pl * 4194304
                    + (size_t)(mtile0 + wm * 4 + mt) * 2048 + ks * 1024 + lane * 16);

    float best[4][4];
    int   bidx[4][4];
#pragma unroll
    for (int mt = 0; mt < 4; ++mt)
#pragma unroll
        for (int r = 0; r < 4; ++r) { best[mt][r] = 3.4e38f; bidx[mt][r] = 0; }

    const char* BgB = (const char*)Bg;
    // prefetch tile 0 (48 KB / 512 thr = 6 x uint4 each; verbatim layout)
    uint4 pf[6];
#pragma unroll
    for (int i = 0; i < 6; ++i) {
        int c = tid + i * 512, pl = c >> 10, r = c & 1023;
        pf[i] = *(const uint4*)(BgB + (size_t)pl * 262144 + r * 16);
    }

    const int paArr[6] = {0, 2, 1, 0, 1, 0};   // pass order small->large
    const int pbArr[6] = {2, 0, 1, 1, 0, 0};

    for (int it = 0; it < 16; ++it) {
        // commit prefetched tile to LDS (prev iter's tail barrier made it safe)
#pragma unroll
        for (int i = 0; i < 6; ++i) { int c = tid + i * 512; *(uint4*)(Bs + c * 16) = pf[i]; }
        __syncthreads();

        // issue next tile's global loads now; they fly during the MFMAs
        if (it < 15) {
#pragma unroll
            for (int i = 0; i < 6; ++i) {
                int c = tid + i * 512, pl = c >> 10, r = c & 1023;
                pf[i] = *(const uint4*)(BgB + (size_t)pl * 262144
                                        + (size_t)(it + 1) * 16384 + r * 16);
            }
        }

        f32x4 acc[4][2];
#pragma unroll
        for (int mt = 0; mt < 4; ++mt)
#pragma unroll
            for (int nt = 0; nt < 2; ++nt) acc[mt][nt] = {0.f, 0.f, 0.f, 0.f};

#pragma unroll
        for (int pass = 0; pass < 6; ++pass) {
            const int aPl = paArr[pass];
            const int bPl = pbArr[pass] * 16384;
#pragma unroll
            for (int ks = 0; ks < 2; ++ks) {
                bf16x8 bf[2];
#pragma unroll
                for (int nt = 0; nt < 2; ++nt)
                    bf[nt] = *(const bf16x8*)(Bs + bPl + (wn * 2 + nt) * 2048
                                              + ks * 1024 + lane * 16);
#pragma unroll
                for (int mt = 0; mt < 4; ++mt)
#pragma unroll
                    for (int nt = 0; nt < 2; ++nt)
                        acc[mt][nt] = __builtin_amdgcn_mfma_f32_16x16x32_bf16(
                            af[aPl][mt][ks], bf[nt], acc[mt][nt], 0, 0, 0);
            }
        }

        // running argmin update; per-(lane,nt) n strictly ascends with it
#pragma unroll
        for (int nt = 0; nt < 2; ++nt) {
            const int n = it * 128 + wn * 32 + nt * 16 + col;
            const float e = esqS[n];
#pragma unroll
            for (int mt = 0; mt < 4; ++mt)
#pragma unroll
                for (int r = 0; r < 4; ++r) {
                    float d = fmaf(-2.f, acc[mt][nt][r], e);
                    if (d < best[mt][r]) { best[mt][r] = d; bidx[mt][r] = n; }
                }
        }
        __syncthreads();   // LDS reads done -> next ds_write safe
    }

    // ---- reduce 16 cols within each quad-group (lexicographic (d, idx) min) ----
    float* redD = (float*)Bs;            // [128 rows][4 wn]
    int*   redI = (int*)(Bs + 2048);
    int*   idxF = (int*)(Bs + 4096);     // [128] final idx
#pragma unroll
    for (int mt = 0; mt < 4; ++mt)
#pragma unroll
        for (int r = 0; r < 4; ++r) {
            float d = best[mt][r];
            int   i = bidx[mt][r];
#pragma unroll
            for (int m = 1; m < 16; m <<= 1) {
                float od = __shfl_xor(d, m, 16);
                int   oi = __shfl_xor(i, m, 16);
                if (od < d || (od == d && oi < i)) { d = od; i = oi; }
            }
            if (col == 0) {
                int row = wm * 64 + mt * 16 + quad * 4 + r;
                redD[row * 4 + wn] = d;
                redI[row * 4 + wn] = i;
            }
        }
    __syncthreads();

    if (tid < 128) {
        float bd = redD[tid * 4]; int bi = redI[tid * 4];
#pragma unroll
        for (int w = 1; w < 4; ++w) {
            float d = redD[tid * 4 + w]; int i = redI[tid * 4 + w];
            if (d < bd || (d == bd && i < bi)) { bd = d; bi = i; }
        }
        out0[bx * 128 + tid] = (float)bi;
        idxF[tid] = bi;
    }
    __syncthreads();

    // ---- fused gather: 128 px x 64 dims from the ORIGINAL fp32 codebook ----
    const int pi = tid & 127, dg = tid >> 7;          // dg: 16 dims each
    const int idx = idxF[pi];
    const float4* src = (const float4*)(cb + (size_t)idx * DIM + dg * 16);
    const int bb = bx >> 3, hw = (bx & 7) * 128 + pi;
    float* o = out1 + (size_t)bb * 65536 + (size_t)(dg * 16) * 1024 + hw;
#pragma unroll
    for (int q = 0; q < 4; ++q) {
        float4 v = src[q];
        o[(size_t)(q * 4 + 0) << 10] = v.x;
        o[(size_t)(q * 4 + 1) << 10] = v.y;
        o[(size_t)(q * 4 + 2) << 10] = v.z;
        o[(size_t)(q * 4 + 3) << 10] = v.w;
    }
}

// ---------------------------------------------------------------------------
extern "C" void kernel_launch(void* const* d_in, const int* in_sizes, int n_in,
                              void* d_out, int out_size, void* d_ws, size_t ws_size,
                              hipStream_t stream) {
    const float* laten = (const float*)d_in[0];   // (32,64,32,32) fp32
    const float* cb    = (const float*)d_in[1];   // (2048,64) fp32

    float* out0 = (float*)d_out;                  // indices as float, N_PIX
    float* out1 = (float*)d_out + N_PIX;          // quant_laten, 2M

    // ws layout: esq 8 KB | Ag 12 MB | Bg 768 KB   (~12.8 MB total)
    float* esq = (float*)d_ws;
    unsigned short* Ag = (unsigned short*)(esq + 2048);
    unsigned short* Bg = Ag + 6291456;            // 12 MB / 2B

    convert_kernel<<<136, 256, 0, stream>>>(laten, cb, Ag, Bg, esq);

    dist_fused_kernel<<<256, 512, 0, stream>>>(Ag, Bg, esq, cb, out0, out1);
}